// Round 1
// baseline (1114.142 us; speedup 1.0000x reference)
//
#include <hip/hip_runtime.h>
#include <stdint.h>

#define Bn 64
#define Sn 512
#define Hn 1024
#define En 768
#define Cn (Hn + En)   // 1792

typedef __bf16 bf16_t;
typedef bf16_t bf16x8 __attribute__((ext_vector_type(8)));
typedef float  f32x4  __attribute__((ext_vector_type(4)));
typedef unsigned int   uint32;
typedef uint32 u32x2   __attribute__((ext_vector_type(2)));
typedef unsigned short ushort_t;

#define BK   64
#define LDSW 72   // 64 + 8 pad (ushorts) -> row stride 144 B, keeps 16B alignment, breaks pow2 banks

// round-to-nearest fp32 -> bf16, pack two into one dword (lo in low half)
__device__ __forceinline__ uint32 pack2_bf16(float a, float b) {
    uint32 ua = __float_as_uint(a) + 0x8000u;
    uint32 ub = __float_as_uint(b) + 0x8000u;
    return (ub & 0xFFFF0000u) | (ua >> 16);
}

// scores[b,s] = sum_c w_combine[b,c] * tanh( (W @ X^T)[c,s] )
// M = 1792 channels (0..1023 text w/ K=1024, 1024..1791 aspect w/ K=768)
__global__ __launch_bounds__(256, 2)
void scores_kernel(const float* __restrict__ text,
                   const float* __restrict__ aspect,
                   const float* __restrict__ w_text,
                   const float* __restrict__ w_aspect,
                   const float* __restrict__ w_combine,
                   float* __restrict__ scores)
{
    __shared__ ushort_t As[128 * LDSW];   // A tile: [m_local][k] bf16
    __shared__ ushort_t Bsh[128 * LDSW];  // B tile: [n_local][k] bf16 (activation rows)
    __shared__ float wc_s[128];
    __shared__ float part[4][64];

    const int b  = blockIdx.z;
    const int m0 = blockIdx.y * 128;   // channel tile base
    const int n0 = blockIdx.x * 128;   // s tile base

    const bool is_text = (m0 < Hn);
    const int K = is_text ? Hn : En;
    const float* Amat = is_text ? (w_text   + (size_t)b * Hn * Hn + (size_t)m0 * Hn)
                                : (w_aspect + (size_t)b * En * En + (size_t)(m0 - Hn) * En);
    const float* Bmat = is_text ? (text   + (size_t)b * Sn * Hn + (size_t)n0 * Hn)
                                : (aspect + (size_t)b * Sn * En + (size_t)n0 * En);

    const int t = threadIdx.x;
    if (t < 128) wc_s[t] = w_combine[(size_t)b * Cn + m0 + t];

    const int wid  = t >> 6;
    const int lane = t & 63;
    const int r16  = lane & 15;   // MFMA row/col selector
    const int q    = lane >> 4;   // quad
    const int wm = (wid & 1) * 64;
    const int wn = (wid >> 1) * 64;

    f32x4 acc[4][4];
    #pragma unroll
    for (int i = 0; i < 4; ++i)
        #pragma unroll
        for (int j = 0; j < 4; ++j)
            acc[i][j] = (f32x4){0.f, 0.f, 0.f, 0.f};

    const int srow = t >> 4;         // staging: 16 rows per pass
    const int scol = (t & 15) * 4;   // staging: 4 floats per thread

    for (int kk = 0; kk < K; kk += BK) {
        __syncthreads();   // protect LDS from previous iteration's reads
        // ---- stage A and B tiles: fp32 global -> bf16 LDS ----
        #pragma unroll
        for (int p = 0; p < 8; ++p) {
            const int r = p * 16 + srow;
            const float* ga = Amat + (size_t)r * K + kk + scol;
            f32x4 va = *(const f32x4*)ga;
            u32x2 pa = { pack2_bf16(va.x, va.y), pack2_bf16(va.z, va.w) };
            *(u32x2*)(&As[r * LDSW + scol]) = pa;
        }
        #pragma unroll
        for (int p = 0; p < 8; ++p) {
            const int r = p * 16 + srow;
            const float* gb = Bmat + (size_t)r * K + kk + scol;
            f32x4 vb = *(const f32x4*)gb;
            u32x2 pb = { pack2_bf16(vb.x, vb.y), pack2_bf16(vb.z, vb.w) };
            *(u32x2*)(&Bsh[r * LDSW + scol]) = pb;
        }
        __syncthreads();
        // ---- compute: 2 k-substeps of 32, 4x4 mfma tiles per wave ----
        #pragma unroll
        for (int ks = 0; ks < 2; ++ks) {
            bf16x8 af[4], bfr[4];
            #pragma unroll
            for (int i = 0; i < 4; ++i)
                af[i] = *(const bf16x8*)(&As[(wm + i * 16 + r16) * LDSW + ks * 32 + q * 8]);
            #pragma unroll
            for (int j = 0; j < 4; ++j)
                bfr[j] = *(const bf16x8*)(&Bsh[(wn + j * 16 + r16) * LDSW + ks * 32 + q * 8]);
            #pragma unroll
            for (int i = 0; i < 4; ++i)
                #pragma unroll
                for (int j = 0; j < 4; ++j)
                    acc[i][j] = __builtin_amdgcn_mfma_f32_16x16x32_bf16(af[i], bfr[j], acc[i][j], 0, 0, 0);
        }
    }

    // ---- epilogue: tanh, * w_combine, reduce over channel rows ----
    // lane holds D[row = wm + i*16 + q*4 + r][col = wn + j*16 + r16]
    #pragma unroll
    for (int j = 0; j < 4; ++j) {
        float sj = 0.f;
        #pragma unroll
        for (int i = 0; i < 4; ++i) {
            #pragma unroll
            for (int r = 0; r < 4; ++r) {
                const int ml = wm + i * 16 + q * 4 + r;
                sj += tanhf(acc[i][j][r]) * wc_s[ml];
            }
        }
        // reduce across the 4 quads (same column, different rows)
        sj += __shfl_xor(sj, 16, 64);
        sj += __shfl_xor(sj, 32, 64);
        if (q == 0) part[wid][j * 16 + r16] = sj;
    }
    __syncthreads();
    if (t < 128) {
        const float tot = (t < 64) ? (part[0][t] + part[1][t])
                                   : (part[2][t - 64] + part[3][t - 64]);
        atomicAdd(&scores[(size_t)b * Sn + n0 + t], tot);
    }
}

__global__ __launch_bounds__(256)
void softmax_kernel(const float* __restrict__ scores, float* __restrict__ weight)
{
    __shared__ float red[4];
    const int b = blockIdx.x, t = threadIdx.x;
    const int lane = t & 63, wid = t >> 6;
    const float v0 = scores[(size_t)b * Sn + t];
    const float v1 = scores[(size_t)b * Sn + 256 + t];
    float m = fmaxf(v0, v1);
    #pragma unroll
    for (int off = 32; off >= 1; off >>= 1) m = fmaxf(m, __shfl_xor(m, off, 64));
    if (lane == 0) red[wid] = m;
    __syncthreads();
    const float M = fmaxf(fmaxf(red[0], red[1]), fmaxf(red[2], red[3]));
    __syncthreads();
    const float e0 = expf(v0 - M), e1 = expf(v1 - M);
    float s = e0 + e1;
    #pragma unroll
    for (int off = 32; off >= 1; off >>= 1) s += __shfl_xor(s, off, 64);
    if (lane == 0) red[wid] = s;
    __syncthreads();
    const float inv = 1.0f / (red[0] + red[1] + red[2] + red[3]);
    weight[(size_t)b * Sn + t]       = e0 * inv;
    weight[(size_t)b * Sn + 256 + t] = e1 * inv;
}

// out[b,h] = sum_s text[b,s,h] * weight[b,s]
__global__ __launch_bounds__(256)
void out_kernel(const float* __restrict__ text, const float* __restrict__ weight,
                float* __restrict__ out)
{
    __shared__ float ws[64];
    const int b = blockIdx.y, sc = blockIdx.x;
    const int t = threadIdx.x;
    if (t < 64) ws[t] = weight[(size_t)b * Sn + sc * 64 + t];
    __syncthreads();
    const float* tb = text + (size_t)b * Sn * Hn + (size_t)sc * 64 * Hn;
    const int h = t * 4;
    f32x4 acc = {0.f, 0.f, 0.f, 0.f};
    for (int s = 0; s < 64; ++s) {
        f32x4 v = *(const f32x4*)(tb + (size_t)s * Hn + h);
        const float w = ws[s];
        acc.x += v.x * w; acc.y += v.y * w; acc.z += v.z * w; acc.w += v.w * w;
    }
    float* o = out + (size_t)b * Hn + h;
    atomicAdd(o + 0, acc.x);
    atomicAdd(o + 1, acc.y);
    atomicAdd(o + 2, acc.z);
    atomicAdd(o + 3, acc.w);
}

extern "C" void kernel_launch(void* const* d_in, const int* in_sizes, int n_in,
                              void* d_out, int out_size, void* d_ws, size_t ws_size,
                              hipStream_t stream)
{
    const float* text      = (const float*)d_in[0];
    const float* aspect    = (const float*)d_in[1];
    const float* w_text    = (const float*)d_in[2];
    const float* w_aspect  = (const float*)d_in[3];
    const float* w_combine = (const float*)d_in[4];

    float* outp   = (float*)d_out;
    float* weight = outp;                       // [B,S] = 32768 floats
    float* outv   = outp + (size_t)Bn * Sn;     // [B,H] = 65536 floats
    float* scores = (float*)d_ws;               // [B,S] scratch

    hipMemsetAsync(scores, 0, (size_t)Bn * Sn * sizeof(float), stream);
    hipMemsetAsync(outv,   0, (size_t)Bn * Hn * sizeof(float), stream);

    scores_kernel<<<dim3(4, 14, Bn), 256, 0, stream>>>(text, aspect, w_text, w_aspect, w_combine, scores);
    softmax_kernel<<<Bn, 256, 0, stream>>>(scores, weight);
    out_kernel<<<dim3(8, Bn), 256, 0, stream>>>(text, weight, outv);
}

// Round 2
// 815.314 us; speedup vs baseline: 1.3665x; 1.3665x over previous
//
#include <hip/hip_runtime.h>
#include <stdint.h>

#define Bn 64
#define Sn 512
#define Hn 1024
#define En 768
#define Cn (Hn + En)   // 1792

typedef __bf16 bf16_t;
typedef bf16_t bf16x8 __attribute__((ext_vector_type(8)));
typedef float  f32x4  __attribute__((ext_vector_type(4)));
typedef unsigned int uint32;
typedef uint32 u32x4 __attribute__((ext_vector_type(4)));
typedef unsigned short ushort_t;

// flat element offsets of the bf16 scratch segments (order: text, aspect, w_text, w_aspect)
#define T_TEXT   33554432u   // 64*512*1024
#define T_ASPECT 58720256u   // + 64*512*768
#define T_WTEXT  125829120u  // + 64*1024*1024
#define T_TOTAL  163577856u  // + 64*768*768
#define WS_BF_BYTES ((size_t)T_TOTAL * 2)

// fp32 -> bf16 (round-half-up), pack two into one dword
__device__ __forceinline__ uint32 pack2_bf16(float a, float b) {
    uint32 ua = __float_as_uint(a) + 0x8000u;
    uint32 ub = __float_as_uint(b) + 0x8000u;
    return (ub & 0xFFFF0000u) | (ua >> 16);
}

// one streaming pass: all 4 fp32 tensors -> bf16 in d_ws (segment bounds are block-aligned)
__global__ __launch_bounds__(256)
void convert_kernel(const float* __restrict__ text, const float* __restrict__ aspect,
                    const float* __restrict__ w_text, const float* __restrict__ w_aspect,
                    ushort_t* __restrict__ dst)
{
    const size_t i = ((size_t)blockIdx.x * 256 + threadIdx.x) * 8;
    const float* src; size_t off;
    if (i < T_TEXT)        { src = text;     off = i; }
    else if (i < T_ASPECT) { src = aspect;   off = i - T_TEXT; }
    else if (i < T_WTEXT)  { src = w_text;   off = i - T_ASPECT; }
    else                   { src = w_aspect; off = i - T_WTEXT; }
    f32x4 a = *(const f32x4*)(src + off);
    f32x4 c = *(const f32x4*)(src + off + 4);
    u32x4 p = { pack2_bf16(a.x, a.y), pack2_bf16(a.z, a.w),
                pack2_bf16(c.x, c.y), pack2_bf16(c.z, c.w) };
    *(u32x4*)(dst + i) = p;
}

// scores[b,s] = sum_c w_combine[b,c] * tanh( (W @ X^T)[c,s] )
// m97-style: global_load_lds dwordx4 staging, XOR-swizzled k-chunks (bank-even ds_read_b128)
__global__ __launch_bounds__(256, 4)
void scores_kernel(const ushort_t* __restrict__ text_bf,
                   const ushort_t* __restrict__ aspect_bf,
                   const ushort_t* __restrict__ wtext_bf,
                   const ushort_t* __restrict__ waspect_bf,
                   const float* __restrict__ w_combine,
                   float* __restrict__ scores)
{
    __shared__ __align__(16) ushort_t As[128 * 64];  // [row][chunk^ (row&7)] bf16, unpadded
    __shared__ __align__(16) ushort_t Bs[128 * 64];
    __shared__ float wc_s[128];
    __shared__ float part[4][64];

    const int b  = blockIdx.z;
    const int m0 = blockIdx.y * 128;   // channel tile base
    const int n0 = blockIdx.x * 128;   // s tile base
    const bool is_text = (m0 < Hn);
    const int K = is_text ? Hn : En;
    const ushort_t* Amat = is_text ? (wtext_bf   + (size_t)b * Hn * Hn + (size_t)m0 * Hn)
                                   : (waspect_bf + (size_t)b * En * En + (size_t)(m0 - Hn) * En);
    const ushort_t* Bmat = is_text ? (text_bf   + (size_t)b * Sn * Hn + (size_t)n0 * Hn)
                                   : (aspect_bf + (size_t)b * Sn * En + (size_t)n0 * En);

    const int t = threadIdx.x;
    if (t < 128) wc_s[t] = w_combine[(size_t)b * Cn + m0 + t];

    const int wid = t >> 6, lane = t & 63;
    const int r16 = lane & 15, q = lane >> 4;
    const int wm = (wid & 1) * 64, wn = (wid >> 1) * 64;

    // staging: wave wid loads rows [wid*32, wid*32+32) in 4 chunks of 8 rows.
    // lane l -> LDS slot (row = l>>3, chunk = l&7); global source chunk = (l&7) ^ (row&7)
    const int lrow   = lane >> 3;
    const int lchunk = (lane & 7) ^ lrow;
    const ushort_t* Ag = Amat + (size_t)(wid * 32 + lrow) * K + lchunk * 8;
    const ushort_t* Bg = Bmat + (size_t)(wid * 32 + lrow) * K + lchunk * 8;

    f32x4 acc[4][4];
    #pragma unroll
    for (int i = 0; i < 4; ++i)
        #pragma unroll
        for (int j = 0; j < 4; ++j)
            acc[i][j] = (f32x4){0.f, 0.f, 0.f, 0.f};

    for (int kk = 0; kk < K; kk += 64) {
        __syncthreads();   // previous iteration's fragment reads done
        #pragma unroll
        for (int c = 0; c < 4; ++c) {
            __builtin_amdgcn_global_load_lds(
                (const __attribute__((address_space(1))) void*)(Ag + (size_t)c * 8 * K + kk),
                (__attribute__((address_space(3))) void*)&As[(wid * 32 + c * 8) * 64], 16, 0, 0);
            __builtin_amdgcn_global_load_lds(
                (const __attribute__((address_space(1))) void*)(Bg + (size_t)c * 8 * K + kk),
                (__attribute__((address_space(3))) void*)&Bs[(wid * 32 + c * 8) * 64], 16, 0, 0);
        }
        __syncthreads();   // implicit vmcnt(0): staged data visible
        #pragma unroll
        for (int ks = 0; ks < 2; ++ks) {
            bf16x8 af[4], bfr[4];
            const int cs = ((ks * 4 + q) ^ (r16 & 7)) * 8;  // swizzled chunk offset (elements)
            #pragma unroll
            for (int i = 0; i < 4; ++i)
                af[i] = *(const bf16x8*)&As[(wm + i * 16 + r16) * 64 + cs];
            #pragma unroll
            for (int j = 0; j < 4; ++j)
                bfr[j] = *(const bf16x8*)&Bs[(wn + j * 16 + r16) * 64 + cs];
            #pragma unroll
            for (int i = 0; i < 4; ++i)
                #pragma unroll
                for (int j = 0; j < 4; ++j)
                    acc[i][j] = __builtin_amdgcn_mfma_f32_16x16x32_bf16(af[i], bfr[j], acc[i][j], 0, 0, 0);
        }
    }

    // epilogue: lane holds D[row = wm+i*16+q*4+r][col = wn+j*16+r16]
    #pragma unroll
    for (int j = 0; j < 4; ++j) {
        float sj = 0.f;
        #pragma unroll
        for (int i = 0; i < 4; ++i)
            #pragma unroll
            for (int r = 0; r < 4; ++r)
                sj += tanhf(acc[i][j][r]) * wc_s[wm + i * 16 + q * 4 + r];
        sj += __shfl_xor(sj, 16, 64);
        sj += __shfl_xor(sj, 32, 64);
        if (q == 0) part[wid][j * 16 + r16] = sj;
    }
    __syncthreads();
    if (t < 128) {
        const float tot = (t < 64) ? (part[0][t] + part[1][t])
                                   : (part[2][t - 64] + part[3][t - 64]);
        atomicAdd(&scores[(size_t)b * Sn + n0 + t], tot);
    }
}

__global__ __launch_bounds__(256)
void softmax_kernel(const float* __restrict__ scores, float* __restrict__ weight)
{
    __shared__ float red[4];
    const int b = blockIdx.x, t = threadIdx.x;
    const int lane = t & 63, wid = t >> 6;
    const float v0 = scores[(size_t)b * Sn + t];
    const float v1 = scores[(size_t)b * Sn + 256 + t];
    float m = fmaxf(v0, v1);
    #pragma unroll
    for (int off = 32; off >= 1; off >>= 1) m = fmaxf(m, __shfl_xor(m, off, 64));
    if (lane == 0) red[wid] = m;
    __syncthreads();
    const float M = fmaxf(fmaxf(red[0], red[1]), fmaxf(red[2], red[3]));
    __syncthreads();
    const float e0 = expf(v0 - M), e1 = expf(v1 - M);
    float s = e0 + e1;
    #pragma unroll
    for (int off = 32; off >= 1; off >>= 1) s += __shfl_xor(s, off, 64);
    if (lane == 0) red[wid] = s;
    __syncthreads();
    const float inv = 1.0f / (red[0] + red[1] + red[2] + red[3]);
    weight[(size_t)b * Sn + t]       = e0 * inv;
    weight[(size_t)b * Sn + 256 + t] = e1 * inv;
}

// out[b,h] = sum_s text[b,s,h] * weight[b,s]; one thread per h-column, no atomics
__global__ __launch_bounds__(256)
void out_kernel(const float* __restrict__ text, const float* __restrict__ weight,
                float* __restrict__ out)
{
    __shared__ float ws[Sn];
    const int b = blockIdx.y, hc = blockIdx.x;
    const int t = threadIdx.x;
    ws[t]       = weight[(size_t)b * Sn + t];
    ws[t + 256] = weight[(size_t)b * Sn + 256 + t];
    __syncthreads();
    const int h = hc * 256 + t;
    const float* tb = text + (size_t)b * Sn * Hn + h;
    float acc = 0.f;
    #pragma unroll 8
    for (int s = 0; s < Sn; ++s)
        acc += tb[(size_t)s * Hn] * ws[s];
    out[(size_t)b * Hn + h] = acc;
}

extern "C" void kernel_launch(void* const* d_in, const int* in_sizes, int n_in,
                              void* d_out, int out_size, void* d_ws, size_t ws_size,
                              hipStream_t stream)
{
    const float* text      = (const float*)d_in[0];
    const float* aspect    = (const float*)d_in[1];
    const float* w_text    = (const float*)d_in[2];
    const float* w_aspect  = (const float*)d_in[3];
    const float* w_combine = (const float*)d_in[4];

    float* outp   = (float*)d_out;
    float* weight = outp;                       // [B,S]
    float* outv   = outp + (size_t)Bn * Sn;     // [B,H]

    ushort_t* bf   = (ushort_t*)d_ws;           // 327 MB of bf16 segments
    float* scores  = (float*)((char*)d_ws + WS_BF_BYTES);   // [B,S] scratch

    const ushort_t* text_bf    = bf;
    const ushort_t* aspect_bf  = bf + T_TEXT;
    const ushort_t* wtext_bf   = bf + T_ASPECT;
    const ushort_t* waspect_bf = bf + T_WTEXT;

    hipMemsetAsync(scores, 0, (size_t)Bn * Sn * sizeof(float), stream);
    convert_kernel<<<T_TOTAL / 8 / 256, 256, 0, stream>>>(text, aspect, w_text, w_aspect, bf);
    scores_kernel<<<dim3(4, 14, Bn), 256, 0, stream>>>(text_bf, aspect_bf, wtext_bf, waspect_bf,
                                                       w_combine, scores);
    softmax_kernel<<<Bn, 256, 0, stream>>>(scores, weight);
    out_kernel<<<dim3(4, Bn), 256, 0, stream>>>(text, weight, outv);
}